// Round 10
// baseline (748.238 us; speedup 1.0000x reference)
//
#include <hip/hip_runtime.h>
#include <math.h>

#define NB 8
#define NREG 64
#define DIM 1024
#define NCHUNK 256               // row chunks; segsum grid = NCHUNK*4

typedef float f4 __attribute__((ext_vector_type(4)));

// ---------------- ws layout (bytes) ----------------
// sums    f32[64*1024]  @ 0        (262144)
// counts  u32[64]       @ 262144   (256)
// scores  f32[64]       @ 262400   (256)
// partial f4[64]        @ 262656   (1024)
// rid     u8[N]         @ 263680   (~100 KB)
#define SUMS_OFF  0
#define CNT_OFF   262144
#define SCORE_OFF 262400
#define PART_OFF  262656
#define RID_OFF   263680

// K1: per-block coords minmax partials + zero accumulators + seed logit. grid 64.
__global__ __launch_bounds__(256) void k_minmax_init(const float2* __restrict__ coords,
                                                     int N,
                                                     float4* __restrict__ partial,
                                                     float* __restrict__ sums,
                                                     unsigned* __restrict__ counts,
                                                     float* __restrict__ scores,
                                                     float* __restrict__ out,
                                                     const float* __restrict__ c2_b) {
    int b = blockIdx.x, t = threadIdx.x;
    ((float4*)sums)[b * 256 + t] = make_float4(0.f, 0.f, 0.f, 0.f);
    if (b == 0) {
        if (t < NREG) { counts[t] = 0u; scores[t] = 0.f; }
        else if (t == 64) out[0] = c2_b[0];
    }
    float mnx = 1e30f, mny = 1e30f, mxx = -1e30f, mxy = -1e30f;
    for (int i = b * 256 + t; i < N; i += 64 * 256) {
        float2 c = coords[i];
        mnx = fminf(mnx, c.x); mny = fminf(mny, c.y);
        mxx = fmaxf(mxx, c.x); mxy = fmaxf(mxy, c.y);
    }
    for (int off = 32; off; off >>= 1) {
        mnx = fminf(mnx, __shfl_xor(mnx, off));
        mny = fminf(mny, __shfl_xor(mny, off));
        mxx = fmaxf(mxx, __shfl_xor(mxx, off));
        mxy = fmaxf(mxy, __shfl_xor(mxy, off));
    }
    __shared__ float s[4][4];
    int w = t >> 6, lane = t & 63;
    if (lane == 0) { s[w][0] = mnx; s[w][1] = mny; s[w][2] = mxx; s[w][3] = mxy; }
    __syncthreads();
    if (t == 0) {
        for (int i = 1; i < 4; ++i) {
            s[0][0] = fminf(s[0][0], s[i][0]);
            s[0][1] = fminf(s[0][1], s[i][1]);
            s[0][2] = fmaxf(s[0][2], s[i][2]);
            s[0][3] = fmaxf(s[0][3], s[i][3]);
        }
        partial[b] = make_float4(s[0][0], s[0][1], s[0][2], s[0][3]);
    }
}

// K2: reduce minmax partials in-block; write rid[i] (u8) + counts histogram.
__global__ __launch_bounds__(256) void k_rid(const float2* __restrict__ coords, int N,
                                             const float4* __restrict__ partial,
                                             unsigned char* __restrict__ rid,
                                             unsigned* __restrict__ counts) {
    __shared__ float prm[4];          // lox, loy, spx, spy
    __shared__ unsigned lcnt[NREG];
    int t = threadIdx.x;
    if (t < NREG) lcnt[t] = 0u;
    if (t < 64) {
        float4 p = partial[t];
        float mnx = p.x, mny = p.y, mxx = p.z, mxy = p.w;
        for (int off = 32; off; off >>= 1) {
            mnx = fminf(mnx, __shfl_xor(mnx, off));
            mny = fminf(mny, __shfl_xor(mny, off));
            mxx = fmaxf(mxx, __shfl_xor(mxx, off));
            mxy = fmaxf(mxy, __shfl_xor(mxy, off));
        }
        if (t == 0) {
            prm[0] = mnx; prm[1] = mny;
            prm[2] = fmaxf(mxx - mnx, 1.0f);
            prm[3] = fmaxf(mxy - mny, 1.0f);
        }
    }
    __syncthreads();
    int i = blockIdx.x * 256 + t;
    if (i < N) {
        float2 c = coords[i];
        float qx = ((c.x - prm[0]) / prm[2]) * (float)NB;
        float qy = ((c.y - prm[1]) / prm[3]) * (float)NB;
        int bx = min(max((int)qx, 0), NB - 1);
        int by = min(max((int)qy, 0), NB - 1);
        int r = by * NB + bx;
        rid[i] = (unsigned char)r;
        atomicAdd(&lcnt[r], 1u);
    }
    __syncthreads();
    if (t < NREG && lcnt[t]) atomicAdd(&counts[t], lcnt[t]);
}

// K3: density-preserving segment sum.
// grid = NCHUNK chunks x 4 region-groups. The 4 blocks of a chunk collectively
// read every row of the chunk exactly once (rid>>4 selects the group), in
// ascending order -> DRAM page-hit density. Per block: compact kept rows into
// an LDS list, 8-deep ILP gather of full 4KB rows, ds_add into [16][1024] f32
// (bank = t%32, conflict-free), one atomic flush.
__global__ __launch_bounds__(256, 2) void k_segsum(const float* __restrict__ x,
                                                   const unsigned char* __restrict__ rid,
                                                   int N, int rpc,
                                                   float* __restrict__ sums) {
    __shared__ float lsum[16 * 1024];       // 64 KB
    __shared__ unsigned short list[512];
    __shared__ int nkept;
    int t = threadIdx.x;
    int grp = blockIdx.x & 3;
    int chunk = blockIdx.x >> 2;
    int row0 = chunk * rpc;
    int nrows = min(N - row0, rpc);
    if (nrows <= 0) return;

    for (int i = t; i < 16 * 1024; i += 256) lsum[i] = 0.f;
    if (t == 0) nkept = 0;
    __syncthreads();

    int lane = t & 63;
    for (int base = 0; base < nrows; base += 256) {
        int rr = base + t;
        unsigned r = (rr < nrows) ? (unsigned)rid[row0 + rr] : 0xFFu;
        bool keep = (rr < nrows) && ((int)(r >> 4) == grp);
        unsigned long long m = __ballot(keep);
        int cnt = __popcll(m);
        if (cnt) {
            int wbase = 0;
            if (lane == 0) wbase = atomicAdd(&nkept, cnt);
            wbase = __shfl(wbase, 0);
            if (keep) {
                int rank = __popcll(m & ((1ull << lane) - 1ull));
                list[wbase + rank] = (unsigned short)(rr | ((r & 15u) << 12));
            }
        }
    }
    __syncthreads();
    int M = nkept;

    const float* xb = x + (size_t)row0 * DIM + t;
    int j = 0;
    for (; j + 8 <= M; j += 8) {
        unsigned e0 = list[j + 0], e1 = list[j + 1], e2 = list[j + 2], e3 = list[j + 3];
        unsigned e4 = list[j + 4], e5 = list[j + 5], e6 = list[j + 6], e7 = list[j + 7];
        const float* p0 = xb + (size_t)(e0 & 0xFFFu) * DIM;
        const float* p1 = xb + (size_t)(e1 & 0xFFFu) * DIM;
        const float* p2 = xb + (size_t)(e2 & 0xFFFu) * DIM;
        const float* p3 = xb + (size_t)(e3 & 0xFFFu) * DIM;
        const float* p4 = xb + (size_t)(e4 & 0xFFFu) * DIM;
        const float* p5 = xb + (size_t)(e5 & 0xFFFu) * DIM;
        const float* p6 = xb + (size_t)(e6 & 0xFFFu) * DIM;
        const float* p7 = xb + (size_t)(e7 & 0xFFFu) * DIM;
        float v0[4], v1[4], v2[4], v3[4], v4[4], v5[4], v6[4], v7[4];
        #pragma unroll
        for (int i = 0; i < 4; ++i) {
            v0[i] = p0[256 * i]; v1[i] = p1[256 * i];
            v2[i] = p2[256 * i]; v3[i] = p3[256 * i];
            v4[i] = p4[256 * i]; v5[i] = p5[256 * i];
            v6[i] = p6[256 * i]; v7[i] = p7[256 * i];
        }
        float* d0 = lsum + (e0 >> 12) * 1024 + t;
        float* d1 = lsum + (e1 >> 12) * 1024 + t;
        float* d2 = lsum + (e2 >> 12) * 1024 + t;
        float* d3 = lsum + (e3 >> 12) * 1024 + t;
        float* d4 = lsum + (e4 >> 12) * 1024 + t;
        float* d5 = lsum + (e5 >> 12) * 1024 + t;
        float* d6 = lsum + (e6 >> 12) * 1024 + t;
        float* d7 = lsum + (e7 >> 12) * 1024 + t;
        #pragma unroll
        for (int i = 0; i < 4; ++i) {
            atomicAdd(d0 + 256 * i, v0[i]); atomicAdd(d1 + 256 * i, v1[i]);
            atomicAdd(d2 + 256 * i, v2[i]); atomicAdd(d3 + 256 * i, v3[i]);
            atomicAdd(d4 + 256 * i, v4[i]); atomicAdd(d5 + 256 * i, v5[i]);
            atomicAdd(d6 + 256 * i, v6[i]); atomicAdd(d7 + 256 * i, v7[i]);
        }
    }
    for (; j < M; ++j) {
        unsigned e = list[j];
        const float* p = xb + (size_t)(e & 0xFFFu) * DIM;
        float* d = lsum + (e >> 12) * 1024 + t;
        #pragma unroll
        for (int i = 0; i < 4; ++i) atomicAdd(d + 256 * i, p[256 * i]);
    }
    __syncthreads();
    float* sg = sums + (size_t)grp * 16 * 1024;     // regions [16g, 16g+16)
    for (int i = t; i < 16 * 1024; i += 256)
        unsafeAtomicAdd(&sg[i], lsum[i]);
}

// K4: gated attention scores, barrier-free: warp w owns attention row a.
__global__ __launch_bounds__(256) void k_scores(const float* __restrict__ sums,
                                                const unsigned* __restrict__ counts,
                                                const float* __restrict__ U_w,
                                                const float* __restrict__ U_b,
                                                const float* __restrict__ V_w,
                                                const float* __restrict__ V_b,
                                                const float* __restrict__ w_w,
                                                float* __restrict__ scores) {
    __shared__ float Us[4][DIM];
    __shared__ float Vs[4][DIM];
    int t = threadIdx.x, w = t >> 6, lane = t & 63;
    int a = blockIdx.x * 4 + w;
    const float4* U4 = (const float4*)(U_w + (size_t)a * DIM);
    const float4* V4 = (const float4*)(V_w + (size_t)a * DIM);
    #pragma unroll
    for (int s = 0; s < 4; ++s) {
        ((float4*)Us[w])[s * 64 + lane] = U4[s * 64 + lane];
        ((float4*)Vs[w])[s * 64 + lane] = V4[s * 64 + lane];
    }
    float ub = U_b[a], vb = V_b[a], ww = w_w[a];
    for (int reg = 0; reg < NREG; ++reg) {
        float inv = 1.0f / fmaxf((float)counts[reg], 1.0f);
        float du = 0.f, dv = 0.f;
        #pragma unroll
        for (int s = 0; s < 4; ++s) {
            float4 sv = ((const float4*)(sums + (size_t)reg * DIM))[s * 64 + lane];
            float4 u4 = ((const float4*)Us[w])[s * 64 + lane];
            float4 v4 = ((const float4*)Vs[w])[s * 64 + lane];
            float rx = sv.x * inv, ry = sv.y * inv, rz = sv.z * inv, rw = sv.w * inv;
            du = fmaf(u4.x, rx, fmaf(u4.y, ry, fmaf(u4.z, rz, fmaf(u4.w, rw, du))));
            dv = fmaf(v4.x, rx, fmaf(v4.y, ry, fmaf(v4.z, rz, fmaf(v4.w, rw, dv))));
        }
        for (int off = 32; off; off >>= 1) {
            du += __shfl_xor(du, off);
            dv += __shfl_xor(dv, off);
        }
        if (lane == 0) {
            float g = tanhf(du + ub) * (1.0f / (1.0f + expf(-(dv + vb))));
            unsafeAtomicAdd(&scores[reg], ww * g);
        }
    }
}

// K5: softmax + slide (redundant per block) + classifier rows. grid 64.
__global__ __launch_bounds__(256) void k_attn_cls(const float* __restrict__ scores,
                                                  const unsigned* __restrict__ counts,
                                                  const float* __restrict__ sums,
                                                  const float* __restrict__ c1_w,
                                                  const float* __restrict__ c1_b,
                                                  const float* __restrict__ c2_w,
                                                  float* __restrict__ out) {
    __shared__ float coef[NREG];
    __shared__ float slide[DIM];
    __shared__ float sp[4];
    int t = threadIdx.x;
    if (t < 64) {
        unsigned cnt = counts[t];
        float sc = (cnt > 0u) ? scores[t] : -INFINITY;
        float m = sc;
        for (int off = 32; off; off >>= 1) m = fmaxf(m, __shfl_xor(m, off));
        float e = expf(sc - m);
        float sum = e;
        for (int off = 32; off; off >>= 1) sum += __shfl_xor(sum, off);
        float a = e / sum;
        if (blockIdx.x == 0) out[1 + DIM + t] = a;
        coef[t] = a / fmaxf((float)cnt, 1.0f);
    }
    __syncthreads();
    f4 acc = (f4)(0.f);
    const f4* sums4 = (const f4*)sums;
    #pragma unroll 8
    for (int reg = 0; reg < NREG; ++reg)
        acc += coef[reg] * sums4[reg * 256 + t];
    ((f4*)slide)[t] = acc;
    if (blockIdx.x == 0) {
        float4 o = make_float4(acc.x, acc.y, acc.z, acc.w);
        ((float4*)(out + 1))[t] = o;
    }
    __syncthreads();
    int w = t >> 6, lane = t & 63;
    int j = blockIdx.x * 4 + w;
    const f4* cw4 = (const f4*)(c1_w + (size_t)j * DIM);
    const f4* sl4 = (const f4*)slide;
    float d = 0.f;
    #pragma unroll
    for (int jj = 0; jj < 4; ++jj) {
        f4 cc = cw4[lane + 64 * jj];
        f4 ss = sl4[lane + 64 * jj];
        d = fmaf(cc.x, ss.x, fmaf(cc.y, ss.y, fmaf(cc.z, ss.z, fmaf(cc.w, ss.w, d))));
    }
    for (int off = 32; off; off >>= 1) d += __shfl_xor(d, off);
    if (lane == 0) sp[w] = fmaxf(d + c1_b[j], 0.f) * c2_w[j];
    __syncthreads();
    if (t == 0) unsafeAtomicAdd(&out[0], sp[0] + sp[1] + sp[2] + sp[3]);
}

extern "C" void kernel_launch(void* const* d_in, const int* in_sizes, int n_in,
                              void* d_out, int out_size, void* d_ws, size_t ws_size,
                              hipStream_t stream) {
    const float*  x      = (const float*)d_in[0];
    const float2* coords = (const float2*)d_in[1];
    const float*  U_w    = (const float*)d_in[2];
    const float*  U_b    = (const float*)d_in[3];
    const float*  V_w    = (const float*)d_in[4];
    const float*  V_b    = (const float*)d_in[5];
    const float*  w_w    = (const float*)d_in[6];
    const float*  c1_w   = (const float*)d_in[7];
    const float*  c1_b   = (const float*)d_in[8];
    const float*  c2_w   = (const float*)d_in[9];
    const float*  c2_b   = (const float*)d_in[10];
    int N = in_sizes[0] / DIM;

    float* out = (float*)d_out;
    char* ws = (char*)d_ws;
    float*         sums    = (float*)(ws + SUMS_OFF);
    unsigned*      counts  = (unsigned*)(ws + CNT_OFF);
    float*         scores  = (float*)(ws + SCORE_OFF);
    float4*        partial = (float4*)(ws + PART_OFF);
    unsigned char* rid     = (unsigned char*)(ws + RID_OFF);

    int rpc = (N + NCHUNK - 1) / NCHUNK;     // rows per chunk (~391), fits 12 bits

    hipLaunchKernelGGL(k_minmax_init, dim3(64), dim3(256), 0, stream,
                       coords, N, partial, sums, counts, scores, out, c2_b);
    hipLaunchKernelGGL(k_rid, dim3((N + 255) / 256), dim3(256), 0, stream,
                       coords, N, partial, rid, counts);
    hipLaunchKernelGGL(k_segsum, dim3(NCHUNK * 4), dim3(256), 0, stream,
                       x, rid, N, rpc, sums);
    hipLaunchKernelGGL(k_scores, dim3(32), dim3(256), 0, stream,
                       sums, counts, U_w, U_b, V_w, V_b, w_w, scores);
    hipLaunchKernelGGL(k_attn_cls, dim3(64), dim3(256), 0, stream,
                       scores, counts, sums, c1_w, c1_b, c2_w, out);
}

// Round 11
// 158.605 us; speedup vs baseline: 4.7176x; 4.7176x over previous
//
#include <hip/hip_runtime.h>
#include <math.h>

#define NB 8
#define NREG 64
#define DIM 1024
#define ADIM 128
#define SUBB 32                  // gather sub-blocks per region in segsum

typedef float f4 __attribute__((ext_vector_type(4)));

// ---------------- ws layout (bytes) ----------------
// sums    f32[64*1024]  @ 0        (262144)
// cursor  u32[64]       @ 262144   (256)   == counts after scatter
// scores  f32[64]       @ 262400   (256)
// partial f4[64]        @ 262656   (1024)  per-block minmax {mnx,mny,mxx,mxy}
// slot    u32[64*CAP]   @ 263680   (~25.6 MB)
#define SUMS_OFF  0
#define CUR_OFF   262144
#define SCORE_OFF 262400
#define PART_OFF  262656
#define SLOT_OFF  263680

// K1: per-block coords minmax partials + zero accumulators + seed logit. grid 64.
__global__ __launch_bounds__(256) void k_minmax_init(const float2* __restrict__ coords,
                                                     int N,
                                                     float4* __restrict__ partial,
                                                     float* __restrict__ sums,
                                                     unsigned* __restrict__ cursor,
                                                     float* __restrict__ scores,
                                                     float* __restrict__ out,
                                                     const float* __restrict__ c2_b) {
    int b = blockIdx.x, t = threadIdx.x;
    ((float4*)sums)[b * 256 + t] = make_float4(0.f, 0.f, 0.f, 0.f);
    if (b == 0) {
        if (t < NREG) { cursor[t] = 0u; scores[t] = 0.f; }
        else if (t == 64) out[0] = c2_b[0];
    }
    float mnx = 1e30f, mny = 1e30f, mxx = -1e30f, mxy = -1e30f;
    for (int i = b * 256 + t; i < N; i += 64 * 256) {
        float2 c = coords[i];
        mnx = fminf(mnx, c.x); mny = fminf(mny, c.y);
        mxx = fmaxf(mxx, c.x); mxy = fmaxf(mxy, c.y);
    }
    for (int off = 32; off; off >>= 1) {
        mnx = fminf(mnx, __shfl_xor(mnx, off));
        mny = fminf(mny, __shfl_xor(mny, off));
        mxx = fmaxf(mxx, __shfl_xor(mxx, off));
        mxy = fmaxf(mxy, __shfl_xor(mxy, off));
    }
    __shared__ float s[4][4];
    int w = t >> 6, lane = t & 63;
    if (lane == 0) { s[w][0] = mnx; s[w][1] = mny; s[w][2] = mxx; s[w][3] = mxy; }
    __syncthreads();
    if (t == 0) {
        for (int i = 1; i < 4; ++i) {
            s[0][0] = fminf(s[0][0], s[i][0]);
            s[0][1] = fminf(s[0][1], s[i][1]);
            s[0][2] = fmaxf(s[0][2], s[i][2]);
            s[0][3] = fmaxf(s[0][3], s[i][3]);
        }
        partial[b] = make_float4(s[0][0], s[0][1], s[0][2], s[0][3]);
    }
}

// K2: reduce minmax partials in-block, then scatter indices into per-region slots.
__global__ __launch_bounds__(256) void k_scatter(const float2* __restrict__ coords, int N,
                                                 const float4* __restrict__ partial,
                                                 unsigned* __restrict__ cursor,
                                                 unsigned* __restrict__ slot, int cap) {
    __shared__ float prm[4];          // lox, loy, spx, spy
    __shared__ unsigned lreg[NREG];
    __shared__ unsigned gbase[NREG];
    int t = threadIdx.x;
    if (t < NREG) lreg[t] = 0u;
    if (t < 64) {
        float4 p = partial[t];
        float mnx = p.x, mny = p.y, mxx = p.z, mxy = p.w;
        for (int off = 32; off; off >>= 1) {
            mnx = fminf(mnx, __shfl_xor(mnx, off));
            mny = fminf(mny, __shfl_xor(mny, off));
            mxx = fmaxf(mxx, __shfl_xor(mxx, off));
            mxy = fmaxf(mxy, __shfl_xor(mxy, off));
        }
        if (t == 0) {
            prm[0] = mnx; prm[1] = mny;
            prm[2] = fmaxf(mxx - mnx, 1.0f);
            prm[3] = fmaxf(mxy - mny, 1.0f);
        }
    }
    __syncthreads();
    int i = blockIdx.x * 256 + t;
    int r = 0; unsigned rank = 0;
    if (i < N) {
        float2 c = coords[i];
        float qx = ((c.x - prm[0]) / prm[2]) * (float)NB;
        float qy = ((c.y - prm[1]) / prm[3]) * (float)NB;
        int bx = min(max((int)qx, 0), NB - 1);
        int by = min(max((int)qy, 0), NB - 1);
        r = by * NB + bx;
        rank = atomicAdd(&lreg[r], 1u);
    }
    __syncthreads();
    if (t < NREG) gbase[t] = lreg[t] ? atomicAdd(&cursor[t], lreg[t]) : 0u;
    __syncthreads();
    if (i < N) slot[(size_t)r * cap + gbase[r] + rank] = (unsigned)i;
}

// K3: segment sum. grid = 64 regions x SUBB sub-blocks (region = bid&63);
// register accumulation, single atomic flush, plain (cached) loads.
__global__ __launch_bounds__(256) void k_segsum(const f4* __restrict__ x4,
                                                const unsigned* __restrict__ slot,
                                                const unsigned* __restrict__ cursor,
                                                int cap,
                                                float* __restrict__ sums) {
    int t = threadIdx.x;
    int r = blockIdx.x & 63;
    int k = blockIdx.x >> 6;
    int cnt = (int)cursor[r];
    int chunk = ((((cnt + SUBB - 1) / SUBB) + 7) & ~7);   // multiple of 8
    int j0 = k * chunk;
    int j1 = min(cnt, j0 + chunk);
    const unsigned* sl = slot + (size_t)r * cap;

    f4 acc = (f4)(0.f);
    int j = j0;
    for (; j + 8 <= j1; j += 8) {
        uint4 ia = *(const uint4*)(sl + j);
        uint4 ib = *(const uint4*)(sl + j + 4);
        f4 v0 = x4[(size_t)ia.x * (DIM / 4) + t];
        f4 v1 = x4[(size_t)ia.y * (DIM / 4) + t];
        f4 v2 = x4[(size_t)ia.z * (DIM / 4) + t];
        f4 v3 = x4[(size_t)ia.w * (DIM / 4) + t];
        f4 v4 = x4[(size_t)ib.x * (DIM / 4) + t];
        f4 v5 = x4[(size_t)ib.y * (DIM / 4) + t];
        f4 v6 = x4[(size_t)ib.z * (DIM / 4) + t];
        f4 v7 = x4[(size_t)ib.w * (DIM / 4) + t];
        acc += v0; acc += v1; acc += v2; acc += v3;
        acc += v4; acc += v5; acc += v6; acc += v7;
    }
    for (; j < j1; ++j) {
        f4 v = x4[(size_t)sl[j] * (DIM / 4) + t];
        acc += v;
    }
    if (j1 > j0) {
        float* dst = sums + (size_t)r * DIM + 4 * t;
        unsafeAtomicAdd(dst + 0, acc.x);
        unsafeAtomicAdd(dst + 1, acc.y);
        unsafeAtomicAdd(dst + 2, acc.z);
        unsafeAtomicAdd(dst + 3, acc.w);
    }
}

// K4: gated attention scores, barrier-free: warp w owns attention row a.
// grid = 64 blocks: (a-quad 0..31) x (reg-half 0..1).
__global__ __launch_bounds__(256) void k_scores(const float* __restrict__ sums,
                                                const unsigned* __restrict__ counts,
                                                const float* __restrict__ U_w,
                                                const float* __restrict__ U_b,
                                                const float* __restrict__ V_w,
                                                const float* __restrict__ V_b,
                                                const float* __restrict__ w_w,
                                                float* __restrict__ scores) {
    __shared__ float Us[4][DIM];
    __shared__ float Vs[4][DIM];
    int t = threadIdx.x, w = t >> 6, lane = t & 63;
    int q = blockIdx.x >> 1;
    int h = blockIdx.x & 1;
    int a = q * 4 + w;
    const float4* U4 = (const float4*)(U_w + (size_t)a * DIM);
    const float4* V4 = (const float4*)(V_w + (size_t)a * DIM);
    #pragma unroll
    for (int s = 0; s < 4; ++s) {
        ((float4*)Us[w])[s * 64 + lane] = U4[s * 64 + lane];
        ((float4*)Vs[w])[s * 64 + lane] = V4[s * 64 + lane];
    }
    float ub = U_b[a], vb = V_b[a], ww = w_w[a];
    // no __syncthreads: each warp reads only its own LDS rows
    int r0 = h * 32;
    for (int reg = r0; reg < r0 + 32; ++reg) {
        float inv = 1.0f / fmaxf((float)counts[reg], 1.0f);
        float du = 0.f, dv = 0.f;
        #pragma unroll
        for (int s = 0; s < 4; ++s) {
            float4 sv = ((const float4*)(sums + (size_t)reg * DIM))[s * 64 + lane];
            float4 u4 = ((const float4*)Us[w])[s * 64 + lane];
            float4 v4 = ((const float4*)Vs[w])[s * 64 + lane];
            float rx = sv.x * inv, ry = sv.y * inv, rz = sv.z * inv, rw = sv.w * inv;
            du = fmaf(u4.x, rx, fmaf(u4.y, ry, fmaf(u4.z, rz, fmaf(u4.w, rw, du))));
            dv = fmaf(v4.x, rx, fmaf(v4.y, ry, fmaf(v4.z, rz, fmaf(v4.w, rw, dv))));
        }
        for (int off = 32; off; off >>= 1) {
            du += __shfl_xor(du, off);
            dv += __shfl_xor(dv, off);
        }
        if (lane == 0) {
            float g = tanhf(du + ub) * (1.0f / (1.0f + expf(-(dv + vb))));
            unsafeAtomicAdd(&scores[reg], ww * g);
        }
    }
}

// K5: softmax over 64 scores (redundant per block); slide slice of 64 cols.
// grid = 16 blocks. Writes attn (block 0) and slide to out[1..1024].
__global__ __launch_bounds__(256) void k_attn_slide(const float* __restrict__ scores,
                                                    const unsigned* __restrict__ counts,
                                                    const float* __restrict__ sums,
                                                    float* __restrict__ out) {
    __shared__ float coef[NREG];
    __shared__ float partial[4][64];
    int t = threadIdx.x;
    if (t < 64) {
        unsigned cnt = counts[t];
        float sc = (cnt > 0u) ? scores[t] : -INFINITY;
        float m = sc;
        for (int off = 32; off; off >>= 1) m = fmaxf(m, __shfl_xor(m, off));
        float e = expf(sc - m);
        float sum = e;
        for (int off = 32; off; off >>= 1) sum += __shfl_xor(sum, off);
        float a = e / sum;
        if (blockIdx.x == 0) out[1 + DIM + t] = a;
        coef[t] = a / fmaxf((float)cnt, 1.0f);
    }
    __syncthreads();
    int lane = t & 63, rg = t >> 6;
    int d = blockIdx.x * 64 + lane;
    float acc = 0.f;
    #pragma unroll
    for (int rr = 0; rr < 16; ++rr) {
        int reg = rg * 16 + rr;
        acc = fmaf(coef[reg], sums[(size_t)reg * DIM + d], acc);
    }
    partial[rg][lane] = acc;
    __syncthreads();
    if (t < 64)
        out[1 + blockIdx.x * 64 + t] =
            partial[0][t] + partial[1][t] + partial[2][t] + partial[3][t];
}

// K6: h = relu(c1_w @ slide + c1_b); logit += c2_w . h  (slide read from out+1)
__global__ __launch_bounds__(256) void k_classifier(const float* __restrict__ c1_w,
                                                    const float* __restrict__ c1_b,
                                                    const float* __restrict__ c2_w,
                                                    const float* __restrict__ slide,
                                                    float* __restrict__ out) {
    int w = threadIdx.x >> 6, lane = threadIdx.x & 63;
    int j = blockIdx.x * 4 + w;
    const float* cw = c1_w + (size_t)j * DIM;
    float acc = 0.f;
    #pragma unroll
    for (int jj = 0; jj < 16; ++jj) {
        int d = lane + jj * 64;
        acc = fmaf(cw[d], slide[d], acc);
    }
    for (int off = 32; off; off >>= 1) acc += __shfl_xor(acc, off);
    __shared__ float sp[4];
    if (lane == 0) sp[w] = fmaxf(acc + c1_b[j], 0.f) * c2_w[j];
    __syncthreads();
    if (threadIdx.x == 0) unsafeAtomicAdd(&out[0], sp[0] + sp[1] + sp[2] + sp[3]);
}

extern "C" void kernel_launch(void* const* d_in, const int* in_sizes, int n_in,
                              void* d_out, int out_size, void* d_ws, size_t ws_size,
                              hipStream_t stream) {
    const float*  x      = (const float*)d_in[0];
    const float2* coords = (const float2*)d_in[1];
    const float*  U_w    = (const float*)d_in[2];
    const float*  U_b    = (const float*)d_in[3];
    const float*  V_w    = (const float*)d_in[4];
    const float*  V_b    = (const float*)d_in[5];
    const float*  w_w    = (const float*)d_in[6];
    const float*  c1_w   = (const float*)d_in[7];
    const float*  c1_b   = (const float*)d_in[8];
    const float*  c2_w   = (const float*)d_in[9];
    const float*  c2_b   = (const float*)d_in[10];
    int N = in_sizes[0] / DIM;

    float* out = (float*)d_out;
    char* ws = (char*)d_ws;
    float*    sums    = (float*)(ws + SUMS_OFF);
    unsigned* cursor  = (unsigned*)(ws + CUR_OFF);
    float*    scores  = (float*)(ws + SCORE_OFF);
    float4*   partial = (float4*)(ws + PART_OFF);
    unsigned* slot    = (unsigned*)(ws + SLOT_OFF);
    int cap = (N + 7) & ~7;

    hipLaunchKernelGGL(k_minmax_init, dim3(64), dim3(256), 0, stream,
                       coords, N, partial, sums, cursor, scores, out, c2_b);
    hipLaunchKernelGGL(k_scatter, dim3((N + 255) / 256), dim3(256), 0, stream,
                       coords, N, partial, cursor, slot, cap);
    hipLaunchKernelGGL(k_segsum, dim3(NREG * SUBB), dim3(256), 0, stream,
                       (const f4*)x, slot, cursor, cap, sums);
    hipLaunchKernelGGL(k_scores, dim3(64), dim3(256), 0, stream,
                       sums, cursor, U_w, U_b, V_w, V_b, w_w, scores);
    hipLaunchKernelGGL(k_attn_slide, dim3(16), dim3(256), 0, stream,
                       scores, cursor, sums, out);
    hipLaunchKernelGGL(k_classifier, dim3(NREG), dim3(256), 0, stream,
                       c1_w, c1_b, c2_w, out + 1, out);
}